// Round 11
// baseline (203.293 us; speedup 1.0000x reference)
//
#include <hip/hip_runtime.h>
#include <stdint.h>

// Problem constants
#define NUM_C 1000
#define NB    4096
#define NCOL  9192          // NB + NUM_C + NO
#define NPAD  9216          // 36 * 256
#define DK    512
#define BM    128
#define BN    256
#define BKB   32            // K-slab bytes per row (32 fp8 elems)
#define INV_T 10.0f
#define NBLK  (36 * 32)     // gemm grid size

typedef __attribute__((ext_vector_type(4))) float f32x4;

// workspace layout (bytes)
#define OFF_FALL  0u                 // fp8 [NPAD][DK] = 4,718,592 B
#define OFF_CNTP  4718592u           // uint[1024][16] partial hist (targets+pseudo)
#define OFF_CNTTP 4784128u           // uint[1024][16] partial hist (targets only)
#define OFF_S     4849664u           // float[4096]
#define OFF_P     4866048u           // float[4096]  (contiguous after S)
#define OFF_DONE  4882432u           // uint done-counter (right after P)

__device__ __forceinline__ void async16(const void* g, void* l) {
  __builtin_amdgcn_global_load_lds((const __attribute__((address_space(1))) void*)g,
                                   (__attribute__((address_space(3))) void*)l,
                                   16, 0, 0);
}

// f32 -> e4m3fn (OCP), software RNE fallback
__device__ __forceinline__ unsigned sw_e4m3(float x) {
  float ax = fabsf(x);
  unsigned s = (__float_as_uint(x) >> 24) & 0x80u;
  if (ax < 0.015625f) {
    int n = (int)rintf(ax * 512.0f);
    if (n >= 8) return s | 0x08u;
    return s | (unsigned)n;
  }
  if (ax >= 448.0f) return s | 0x7Eu;
  unsigned u = __float_as_uint(ax);
  int ee = (int)(u >> 23) - 127;
  float scale = __uint_as_float((unsigned)(3 - ee + 127) << 23);
  int qv = (int)rintf(ax * scale);
  if (qv == 16) { ee++; qv = 8; }
  return s | (unsigned)(((ee + 7) << 3) | (qv - 8));
}

template <bool HI>
__device__ __forceinline__ int cvt2(float a, float b, int old) {
#if __has_builtin(__builtin_amdgcn_cvt_pk_fp8_f32)
  return __builtin_amdgcn_cvt_pk_fp8_f32(a, b, old, HI);
#else
  unsigned pk = sw_e4m3(a) | (sw_e4m3(b) << 8);
  return HI ? (int)(((unsigned)old & 0x0000FFFFu) | (pk << 16))
            : (int)(((unsigned)old & 0xFFFF0000u) | pk);
#endif
}

// concat f32->fp8 into fall[NPAD][DK]; blocks 0..15: partial histograms
// (layout [class][16]); blocks 16..48: zero S/P/done
__global__ __launch_bounds__(256) void prep_k(const float* __restrict__ centers,
                                              const float* __restrict__ feats,
                                              const float* __restrict__ ood,
                                              const int* __restrict__ targets,
                                              const int* __restrict__ pseudo,
                                              unsigned char* __restrict__ fall,
                                              unsigned* __restrict__ cntP,
                                              unsigned* __restrict__ cntTP,
                                              unsigned* __restrict__ SPD) {
  __shared__ unsigned hc[1024];
  __shared__ unsigned hct[1024];
  const int tid = threadIdx.x;

  int idx = blockIdx.x * 256 + tid;      // one 16-elem chunk each; 9216*32 total
  int row = idx >> 5;
  int ck  = (idx & 31) * 16;
  const float* src = nullptr;
  if (row < NB)              src = feats   + (size_t)row * DK + ck;
  else if (row < NB + NUM_C) src = centers + (size_t)(row - NB) * DK + ck;
  else if (row < NCOL)       src = ood     + (size_t)(row - NB - NUM_C) * DK + ck;
  unsigned w[4] = {0u, 0u, 0u, 0u};
  if (src) {
#pragma unroll
    for (int g = 0; g < 4; g++) {
      float4 v0 = *(const float4*)(src + g * 4);
      int p = 0;
      p = cvt2<false>(v0.x, v0.y, p);
      p = cvt2<true>(v0.z, v0.w, p);
      w[g] = (unsigned)p;
    }
  }
  *(uint4*)(fall + (size_t)row * DK + ck) = make_uint4(w[0], w[1], w[2], w[3]);

  if (blockIdx.x < 16) {
    for (int k = tid; k < 1024; k += 256) { hc[k] = 0u; hct[k] = 0u; }
    __syncthreads();
    int i = blockIdx.x * 256 + tid;      // 0..4095
    int t = targets[i];
    atomicAdd(&hc[t], 1u);
    atomicAdd(&hct[t], 1u);
    atomicAdd(&hc[pseudo[i]], 1u);
    __syncthreads();
    for (int k = tid; k < 1024; k += 256) {
      cntP[k * 16 + blockIdx.x]  = hc[k];     // transposed: class-major
      cntTP[k * 16 + blockIdx.x] = hct[k];
    }
  } else if (blockIdx.x < 49) {
    int i = (blockIdx.x - 16) * 256 + tid;
    if (i < 8193) SPD[i] = 0u;   // zeros S[4096], P[4096], done (fp32 0.0 == 0u)
  }
}

// Fused fp8 GEMM 128x256 tile, double-buffered LDS (r9 structure),
// + S/P reduction + last-block finalize (done-counter)
__global__ __launch_bounds__(256, 2) void gemm_fused(const unsigned char* __restrict__ fall,
                                                     const int* __restrict__ targets,
                                                     const int* __restrict__ pseudo,
                                                     const unsigned* __restrict__ cntP,
                                                     const unsigned* __restrict__ cntTP,
                                                     float* __restrict__ Sacc,
                                                     float* __restrict__ Pacc,
                                                     unsigned* __restrict__ done,
                                                     float* __restrict__ out) {
  __shared__ unsigned char As[2][BM * BKB];   // 2 x 4 KB
  __shared__ unsigned char Bs[2][BN * BKB];   // 2 x 8 KB
  __shared__ int    sLbl[BN];
  __shared__ float  sRw0[BN];
  __shared__ float  sRw1[BN];
  __shared__ int    sTgt[BM];
  __shared__ int    sLast;
  __shared__ float  red[4];

  const int tid   = threadIdx.x;
  const int nTile = blockIdx.x;   // 36
  const int mTile = blockIdx.y;   // 32
  const int lane  = tid & 63;
  const int wv    = tid >> 6;     // wave 0..3
  const int wm    = wv >> 1;      // row half (64 rows)
  const int wn    = wv & 1;       // col half (128 cols)
  const int q     = lane >> 4;    // k-quad
  const int cIdx  = lane & 15;

  const int aRow0 = mTile * BM;
  const int bRow0 = nTile * BN;

  // Staging: LDS lane-linear (tid*16); swizzle in the global source:
  // slot (row, cs) holds global 16B chunk cg = cs ^ (row&1).
  const int sRow = tid >> 1;                 // 0..127
  const int cg   = (tid & 1) ^ (sRow & 1);
  const unsigned char* gA  = fall + (size_t)(aRow0 + sRow)       * DK + cg * 16;
  const unsigned char* gB0 = fall + (size_t)(bRow0 + sRow)       * DK + cg * 16;
  const unsigned char* gB1 = fall + (size_t)(bRow0 + 128 + sRow) * DK + cg * 16;
  const int lOff = tid * 16;

  // prologue: DMA k-slab 0 into buffer 0 (overlaps with table build below)
  async16(gA,        &As[0][lOff]);
  async16(gB0,       &Bs[0][lOff]);
  async16(gB1,       &Bs[0][lOff + 4096]);

  // per-column tables (lbl, 1/w, 1/(w-1)); per-row targets. w = 1 + sum of partials.
  {
    int j = nTile * BN + tid;
    int lbl, tac;
    if (j >= NCOL)         { lbl = -1; tac = -1; }
    else if (j < NB)       { tac = targets[j]; lbl = tac; }
    else if (j < NB+NUM_C) { tac = j - NB;     lbl = tac; }
    else                   { tac = pseudo[j - NB - NUM_C]; lbl = NUM_C; }
    sLbl[tid] = lbl;
    if (tac >= 0) {
      const uint4* p4 = (const uint4*)(cntP + tac * 16);
      uint4 a0 = p4[0], a1 = p4[1], a2 = p4[2], a3 = p4[3];
      unsigned c = 1u + a0.x + a0.y + a0.z + a0.w + a1.x + a1.y + a1.z + a1.w
                      + a2.x + a2.y + a2.z + a2.w + a3.x + a3.y + a3.z + a3.w;
      float w = (float)c;
      sRw0[tid] = 1.0f / w;
      sRw1[tid] = 1.0f / (w - 1.0f);  // only selected when a positive exists => w>=2
    } else {
      sRw0[tid] = 0.f;
      sRw1[tid] = 0.f;
    }
    if (tid < BM) sTgt[tid] = targets[mTile * BM + tid];
  }

  f32x4 acc[4][8];
#pragma unroll
  for (int mi = 0; mi < 4; mi++)
#pragma unroll
    for (int ni = 0; ni < 8; ni++)
      acc[mi][ni] = (f32x4){0.f, 0.f, 0.f, 0.f};

  // read-side: global chunk cn = q>>1 sits at slot (q>>1) ^ (row&1); row&1 == cIdx&1
  const int fOff = ((((q >> 1) ^ (cIdx & 1)) << 4) | ((q & 1) << 3));

  __syncthreads();   // tables ready + (auto vmcnt drain) slab 0 landed

#pragma unroll
  for (int it = 0; it < 16; it++) {
    const int cur = it & 1;
    const int nxt = cur ^ 1;
    if (it < 15) {   // prefetch next slab into the other buffer; overlaps MFMA below
      const int kt = (it + 1) * BKB;
      async16(gA + kt,  &As[nxt][lOff]);
      async16(gB0 + kt, &Bs[nxt][lOff]);
      async16(gB1 + kt, &Bs[nxt][lOff + 4096]);
    }

    long long af[4];
    long long bf8[8];
#pragma unroll
    for (int mi = 0; mi < 4; mi++)
      af[mi] = *(const long long*)&As[cur][(wm * 64 + mi * 16 + cIdx) * BKB + fOff];
#pragma unroll
    for (int ni = 0; ni < 8; ni++)
      bf8[ni] = *(const long long*)&Bs[cur][(wn * 128 + ni * 16 + cIdx) * BKB + fOff];
#pragma unroll
    for (int mi = 0; mi < 4; mi++)
#pragma unroll
      for (int ni = 0; ni < 8; ni++)
        acc[mi][ni] = __builtin_amdgcn_mfma_f32_16x16x32_fp8_fp8(af[mi], bf8[ni], acc[mi][ni], 0, 0, 0);

    __syncthreads();  // everyone done reading cur; next-iter DMA drains here
  }

  // Epilogue: l = acc*10; S += exp(l-10) * (diag?0 : pos?1/(w-1) : 1/w); P += pos?l:0
  float vS[16], vP[16];
#pragma unroll
  for (int s = 0; s < 16; s++) { vS[s] = 0.f; vP[s] = 0.f; }

#pragma unroll
  for (int ni = 0; ni < 8; ni++) {
    int jloc = wn * 128 + ni * 16 + cIdx;
    int j    = nTile * BN + jloc;
    int lblj = sLbl[jloc];
    float rw0 = sRw0[jloc], rw1 = sRw1[jloc];
#pragma unroll
    for (int mi = 0; mi < 4; mi++) {
      f32x4 a = acc[mi][ni];
#pragma unroll
      for (int r = 0; r < 4; r++) {
        int iloc = wm * 64 + mi * 16 + q * 4 + r;
        int i    = mTile * BM + iloc;
        int ti   = sTgt[iloc];
        float l  = a[r] * INV_T;
        bool diag = (j == i);
        bool pos  = (lblj == ti) && !diag;
        float rw  = diag ? 0.0f : (pos ? rw1 : rw0);
        float e   = __expf(l - 10.0f) * rw;
        vS[mi * 4 + r] += e;
        vP[mi * 4 + r] += pos ? l : 0.0f;
      }
    }
  }

  // fully-static value-halving butterfly over the 16 cIdx lanes (15 shuffle pairs)
#define RED_STEP(m, s, h)                                        \
  {                                                              \
    float sendS = (cIdx & (m)) ? vS[(s)] : vS[(s) + (h)];        \
    float sendP = (cIdx & (m)) ? vP[(s)] : vP[(s) + (h)];        \
    float rS = __shfl_xor(sendS, (m), 64);                       \
    float rP = __shfl_xor(sendP, (m), 64);                       \
    vS[(s)] = ((cIdx & (m)) ? vS[(s) + (h)] : vS[(s)]) + rS;     \
    vP[(s)] = ((cIdx & (m)) ? vP[(s) + (h)] : vP[(s)]) + rP;     \
  }
  RED_STEP(8, 0, 8) RED_STEP(8, 1, 8) RED_STEP(8, 2, 8) RED_STEP(8, 3, 8)
  RED_STEP(8, 4, 8) RED_STEP(8, 5, 8) RED_STEP(8, 6, 8) RED_STEP(8, 7, 8)
  RED_STEP(4, 0, 4) RED_STEP(4, 1, 4) RED_STEP(4, 2, 4) RED_STEP(4, 3, 4)
  RED_STEP(2, 0, 2) RED_STEP(2, 1, 2)
  RED_STEP(1, 0, 1)
#undef RED_STEP

  {
    int rowLoc = wm * 64 + (cIdx >> 2) * 16 + q * 4 + (cIdx & 3);
    int i = mTile * BM + rowLoc;
    atomicAdd(&Sacc[i], vS[0]);
    atomicAdd(&Pacc[i], vP[0]);
  }

  // last-block finalize: loss = -mean( P/npos - 10 - log S )
  __threadfence();
  if (tid == 0) {
    unsigned old = atomicAdd(done, 1u);
    sLast = (old == NBLK - 1) ? 1 : 0;
  }
  __syncthreads();
  if (sLast) {
    __threadfence();
    float local = 0.f;
    for (int i = tid; i < NB; i += 256) {
      float S  = __hip_atomic_load(&Sacc[i], __ATOMIC_RELAXED, __HIP_MEMORY_SCOPE_AGENT);
      float Pv = __hip_atomic_load(&Pacc[i], __ATOMIC_RELAXED, __HIP_MEMORY_SCOPE_AGENT);
      int t = targets[i];
      const uint4* p4 = (const uint4*)(cntTP + t * 16);
      uint4 a0 = p4[0], a1 = p4[1], a2 = p4[2], a3 = p4[3];
      unsigned c = a0.x + a0.y + a0.z + a0.w + a1.x + a1.y + a1.z + a1.w
                 + a2.x + a2.y + a2.z + a2.w + a3.x + a3.y + a3.z + a3.w;
      local += Pv / (float)c - INV_T - __logf(S);
    }
    for (int m = 1; m < 64; m <<= 1) local += __shfl_xor(local, m, 64);
    if ((tid & 63) == 0) red[tid >> 6] = local;
    __syncthreads();
    if (tid == 0) {
      float t = red[0] + red[1] + red[2] + red[3];
      out[0] = -t / (float)NB;
    }
  }
}

extern "C" void kernel_launch(void* const* d_in, const int* in_sizes, int n_in,
                              void* d_out, int out_size, void* d_ws, size_t ws_size,
                              hipStream_t stream) {
  const float* centers = (const float*)d_in[0];   // [1000][512] f32
  const float* feats   = (const float*)d_in[1];   // [4096][512] f32
  const int*   targets = (const int*)d_in[2];     // [4096] i32
  const float* ood     = (const float*)d_in[3];   // [4096][512] f32
  const int*   pseudo  = (const int*)d_in[4];     // [4096] i32

  char* ws = (char*)d_ws;
  unsigned char* fall  = (unsigned char*)(ws + OFF_FALL);
  unsigned*      cntP  = (unsigned*)(ws + OFF_CNTP);
  unsigned*      cntTP = (unsigned*)(ws + OFF_CNTTP);
  float*         Sacc  = (float*)(ws + OFF_S);
  float*         Pacc  = (float*)(ws + OFF_P);
  unsigned*      done  = (unsigned*)(ws + OFF_DONE);

  prep_k<<<dim3((NPAD * 32) / 256), 256, 0, stream>>>(centers, feats, ood, targets, pseudo,
                                                      fall, cntP, cntTP, (unsigned*)(ws + OFF_S));
  gemm_fused<<<dim3(NPAD / BN, NB / BM), 256, 0, stream>>>(fall, targets, pseudo, cntP, cntTP,
                                                           Sacc, Pacc, done, (float*)d_out);
}

// Round 12
// 140.429 us; speedup vs baseline: 1.4477x; 1.4477x over previous
//
#include <hip/hip_runtime.h>
#include <stdint.h>

// Problem constants
#define NUM_C 1000
#define NB    4096
#define NCOL  9192          // NB + NUM_C + NO
#define NPAD  9216          // 36 * 256
#define DK    512
#define BM    128
#define BN    256
#define BKB   32            // K-slab bytes per row (32 fp8 elems)
#define INV_T 10.0f

typedef __attribute__((ext_vector_type(4))) float f32x4;

// workspace layout (bytes)
#define OFF_FALL  0u                 // fp8 [NPAD][DK] = 4,718,592 B
#define OFF_CNTP  4718592u           // uint[16][1024] partial hist (targets+pseudo)
#define OFF_CNTTP 4784128u           // uint[16][1024] partial hist (targets only)
#define OFF_S     4849664u           // float[4096]
#define OFF_P     4866048u           // float[4096]  (contiguous after S)

__device__ __forceinline__ void async16(const void* g, void* l) {
  __builtin_amdgcn_global_load_lds((const __attribute__((address_space(1))) void*)g,
                                   (__attribute__((address_space(3))) void*)l,
                                   16, 0, 0);
}

// f32 -> e4m3fn (OCP), software RNE fallback
__device__ __forceinline__ unsigned sw_e4m3(float x) {
  float ax = fabsf(x);
  unsigned s = (__float_as_uint(x) >> 24) & 0x80u;
  if (ax < 0.015625f) {
    int n = (int)rintf(ax * 512.0f);
    if (n >= 8) return s | 0x08u;
    return s | (unsigned)n;
  }
  if (ax >= 448.0f) return s | 0x7Eu;
  unsigned u = __float_as_uint(ax);
  int ee = (int)(u >> 23) - 127;
  float scale = __uint_as_float((unsigned)(3 - ee + 127) << 23);
  int qv = (int)rintf(ax * scale);
  if (qv == 16) { ee++; qv = 8; }
  return s | (unsigned)(((ee + 7) << 3) | (qv - 8));
}

template <bool HI>
__device__ __forceinline__ int cvt2(float a, float b, int old) {
#if __has_builtin(__builtin_amdgcn_cvt_pk_fp8_f32)
  return __builtin_amdgcn_cvt_pk_fp8_f32(a, b, old, HI);
#else
  unsigned pk = sw_e4m3(a) | (sw_e4m3(b) << 8);
  return HI ? (int)(((unsigned)old & 0x0000FFFFu) | (pk << 16))
            : (int)(((unsigned)old & 0xFFFF0000u) | pk);
#endif
}

// concat f32->fp8 into fall[NPAD][DK]; blocks 0..15: partial histograms; 16..47: zero S/P
__global__ __launch_bounds__(256) void prep_k(const float* __restrict__ centers,
                                              const float* __restrict__ feats,
                                              const float* __restrict__ ood,
                                              const int* __restrict__ targets,
                                              const int* __restrict__ pseudo,
                                              unsigned char* __restrict__ fall,
                                              unsigned* __restrict__ cntP,
                                              unsigned* __restrict__ cntTP,
                                              float* __restrict__ SP) {
  __shared__ unsigned hc[1024];
  __shared__ unsigned hct[1024];
  const int tid = threadIdx.x;

  int idx = blockIdx.x * 256 + tid;      // one 16-elem chunk each; 9216*32 total
  int row = idx >> 5;
  int ck  = (idx & 31) * 16;
  const float* src = nullptr;
  if (row < NB)              src = feats   + (size_t)row * DK + ck;
  else if (row < NB + NUM_C) src = centers + (size_t)(row - NB) * DK + ck;
  else if (row < NCOL)       src = ood     + (size_t)(row - NB - NUM_C) * DK + ck;
  unsigned w[4] = {0u, 0u, 0u, 0u};
  if (src) {
#pragma unroll
    for (int g = 0; g < 4; g++) {
      float4 v0 = *(const float4*)(src + g * 4);
      int p = 0;
      p = cvt2<false>(v0.x, v0.y, p);
      p = cvt2<true>(v0.z, v0.w, p);
      w[g] = (unsigned)p;
    }
  }
  *(uint4*)(fall + (size_t)row * DK + ck) = make_uint4(w[0], w[1], w[2], w[3]);

  if (blockIdx.x < 16) {
    for (int k = tid; k < 1024; k += 256) { hc[k] = 0u; hct[k] = 0u; }
    __syncthreads();
    int i = blockIdx.x * 256 + tid;      // 0..4095
    int t = targets[i];
    atomicAdd(&hc[t], 1u);
    atomicAdd(&hct[t], 1u);
    atomicAdd(&hc[pseudo[i]], 1u);
    __syncthreads();
    for (int k = tid; k < 1024; k += 256) {
      cntP[blockIdx.x * 1024 + k]  = hc[k];
      cntTP[blockIdx.x * 1024 + k] = hct[k];
    }
  } else if (blockIdx.x < 48) {
    SP[(blockIdx.x - 16) * 256 + tid] = 0.0f;   // zeros S[4096] then P[4096]
  }
}

// Fused fp8 GEMM 128x256 tile, 4-SLAB ring pipeline, raw s_barrier + vmcnt(6)
// (never vmcnt(0) in steady state) + S/P reduction epilogue
__global__ __launch_bounds__(256, 2) void gemm_fused(const unsigned char* __restrict__ fall,
                                                     const int* __restrict__ targets,
                                                     const int* __restrict__ pseudo,
                                                     const unsigned* __restrict__ cntP,
                                                     float* __restrict__ Sacc,
                                                     float* __restrict__ Pacc) {
  __shared__ unsigned char As[4][BM * BKB];   // 4 x 4 KB
  __shared__ unsigned char Bs[4][BN * BKB];   // 4 x 8 KB
  __shared__ int    sLbl[BN];
  __shared__ float  sRw0[BN];
  __shared__ float  sRw1[BN];
  __shared__ int    sTgt[BM];

  const int tid   = threadIdx.x;
  const int nTile = blockIdx.x;   // 36
  const int mTile = blockIdx.y;   // 32
  const int lane  = tid & 63;
  const int wv    = tid >> 6;     // wave 0..3
  const int wm    = wv >> 1;      // row half (64 rows)
  const int wn    = wv & 1;       // col half (128 cols)
  const int q     = lane >> 4;    // k-quad
  const int cIdx  = lane & 15;

  const int aRow0 = mTile * BM;
  const int bRow0 = nTile * BN;

  // per-column tables (lbl, 1/w, 1/(w-1)); per-row targets. w = 1 + sum of partials.
  {
    int j = nTile * BN + tid;
    int lbl, tac;
    if (j >= NCOL)         { lbl = -1; tac = -1; }
    else if (j < NB)       { tac = targets[j]; lbl = tac; }
    else if (j < NB+NUM_C) { tac = j - NB;     lbl = tac; }
    else                   { tac = pseudo[j - NB - NUM_C]; lbl = NUM_C; }
    sLbl[tid] = lbl;
    if (tac >= 0) {
      unsigned c = 1u;
#pragma unroll
      for (int b = 0; b < 16; b++) c += cntP[b * 1024 + tac];
      float w = (float)c;
      sRw0[tid] = 1.0f / w;
      sRw1[tid] = 1.0f / (w - 1.0f);  // only selected when a positive exists => w>=2
    } else {
      sRw0[tid] = 0.f;
      sRw1[tid] = 0.f;
    }
    if (tid < BM) sTgt[tid] = targets[mTile * BM + tid];
  }
  __syncthreads();   // tables ready (normal barrier, one-time)

  f32x4 acc[4][8];
#pragma unroll
  for (int mi = 0; mi < 4; mi++)
#pragma unroll
    for (int ni = 0; ni < 8; ni++)
      acc[mi][ni] = (f32x4){0.f, 0.f, 0.f, 0.f};

  // Staging: LDS lane-linear (tid*16); swizzle in the global source:
  // slot (row, cs) holds global 16B chunk cg = cs ^ (row&1).
  const int sRow = tid >> 1;                 // 0..127
  const int cg   = (tid & 1) ^ (sRow & 1);
  const unsigned char* gA  = fall + (size_t)(aRow0 + sRow)       * DK + cg * 16;
  const unsigned char* gB0 = fall + (size_t)(bRow0 + sRow)       * DK + cg * 16;
  const unsigned char* gB1 = fall + (size_t)(bRow0 + 128 + sRow) * DK + cg * 16;
  const int lOff = tid * 16;

  // read-side: global chunk cn = q>>1 sits at slot (q>>1) ^ (row&1); row&1 == cIdx&1
  const int fOff = ((((q >> 1) ^ (cIdx & 1)) << 4) | ((q & 1) << 3));

  // issue slab j into ring buffer j&3 (3 vm-instructions per wave)
#define ISSUE(j)                                         \
  {                                                      \
    const int kt = (j) * BKB;                            \
    const int bf = (j) & 3;                              \
    async16(gA  + kt, &As[bf][lOff]);                    \
    async16(gB0 + kt, &Bs[bf][lOff]);                    \
    async16(gB1 + kt, &Bs[bf][lOff + 4096]);             \
  }

  // 3-slab prologue: slabs 0,1,2 in flight (9 vm-instructions)
  ISSUE(0) ISSUE(1) ISSUE(2)

#pragma unroll
  for (int it = 0; it < 16; it++) {
    // own slab `it` landed when <=6 outstanding (2 newer slabs in flight)
    if (it <= 13)      asm volatile("s_waitcnt vmcnt(6)" ::: "memory");
    else if (it == 14) asm volatile("s_waitcnt vmcnt(3)" ::: "memory");
    else               asm volatile("s_waitcnt vmcnt(0)" ::: "memory");
    // raw barrier: all waves' quarters of slab `it` landed; buffer (it+3)&3
    // == (it-1)&3 fully consumed before this point (reads fed MFMAs pre-barrier)
    asm volatile("s_barrier" ::: "memory");
    if (it < 13) ISSUE(it + 3)

    const int cur = it & 3;
    long long af[4];
    long long bf8[8];
#pragma unroll
    for (int mi = 0; mi < 4; mi++)
      af[mi] = *(const long long*)&As[cur][(wm * 64 + mi * 16 + cIdx) * BKB + fOff];
#pragma unroll
    for (int ni = 0; ni < 8; ni++)
      bf8[ni] = *(const long long*)&Bs[cur][(wn * 128 + ni * 16 + cIdx) * BKB + fOff];
#pragma unroll
    for (int mi = 0; mi < 4; mi++)
#pragma unroll
      for (int ni = 0; ni < 8; ni++)
        acc[mi][ni] = __builtin_amdgcn_mfma_f32_16x16x32_fp8_fp8(af[mi], bf8[ni], acc[mi][ni], 0, 0, 0);
  }
#undef ISSUE

  // Epilogue: l = acc*10; S += exp(l-10) * (diag?0 : pos?1/(w-1) : 1/w); P += pos?l:0
  float vS[16], vP[16];
#pragma unroll
  for (int s = 0; s < 16; s++) { vS[s] = 0.f; vP[s] = 0.f; }

#pragma unroll
  for (int ni = 0; ni < 8; ni++) {
    int jloc = wn * 128 + ni * 16 + cIdx;
    int j    = nTile * BN + jloc;
    int lblj = sLbl[jloc];
    float rw0 = sRw0[jloc], rw1 = sRw1[jloc];
#pragma unroll
    for (int mi = 0; mi < 4; mi++) {
      f32x4 a = acc[mi][ni];
#pragma unroll
      for (int r = 0; r < 4; r++) {
        int iloc = wm * 64 + mi * 16 + q * 4 + r;
        int i    = mTile * BM + iloc;
        int ti   = sTgt[iloc];
        float l  = a[r] * INV_T;
        bool diag = (j == i);
        bool pos  = (lblj == ti) && !diag;
        float rw  = diag ? 0.0f : (pos ? rw1 : rw0);
        float e   = __expf(l - 10.0f) * rw;
        vS[mi * 4 + r] += e;
        vP[mi * 4 + r] += pos ? l : 0.0f;
      }
    }
  }

  // fully-static value-halving butterfly over the 16 cIdx lanes (15 shuffle pairs)
#define RED_STEP(m, s, h)                                        \
  {                                                              \
    float sendS = (cIdx & (m)) ? vS[(s)] : vS[(s) + (h)];        \
    float sendP = (cIdx & (m)) ? vP[(s)] : vP[(s) + (h)];        \
    float rS = __shfl_xor(sendS, (m), 64);                       \
    float rP = __shfl_xor(sendP, (m), 64);                       \
    vS[(s)] = ((cIdx & (m)) ? vS[(s) + (h)] : vS[(s)]) + rS;     \
    vP[(s)] = ((cIdx & (m)) ? vP[(s) + (h)] : vP[(s)]) + rP;     \
  }
  RED_STEP(8, 0, 8) RED_STEP(8, 1, 8) RED_STEP(8, 2, 8) RED_STEP(8, 3, 8)
  RED_STEP(8, 4, 8) RED_STEP(8, 5, 8) RED_STEP(8, 6, 8) RED_STEP(8, 7, 8)
  RED_STEP(4, 0, 4) RED_STEP(4, 1, 4) RED_STEP(4, 2, 4) RED_STEP(4, 3, 4)
  RED_STEP(2, 0, 2) RED_STEP(2, 1, 2)
  RED_STEP(1, 0, 1)
#undef RED_STEP

  {
    int rowLoc = wm * 64 + (cIdx >> 2) * 16 + q * 4 + (cIdx & 3);
    int i = mTile * BM + rowLoc;
    atomicAdd(&Sacc[i], vS[0]);
    atomicAdd(&Pacc[i], vP[0]);
  }
}

// loss = -mean( P/npos - 10 - log S );  npos_i = sum_b cntTP[b][targets[i]]
__global__ __launch_bounds__(256) void finalize_k(const float* __restrict__ S,
                                                  const float* __restrict__ P,
                                                  const int* __restrict__ targets,
                                                  const unsigned* __restrict__ cntTP,
                                                  float* __restrict__ out) {
  __shared__ unsigned ct[1024];
  __shared__ float red[4];
  int tid = threadIdx.x;
  for (int k = tid; k < 1024; k += 256) {
    unsigned c = 0u;
#pragma unroll
    for (int b = 0; b < 16; b++) c += cntTP[b * 1024 + k];
    ct[k] = c;
  }
  __syncthreads();
  float local = 0.f;
  for (int i = tid; i < NB; i += 256) {
    float npos = (float)ct[targets[i]];
    local += P[i] / npos - INV_T - __logf(S[i]);
  }
  for (int m = 1; m < 64; m <<= 1) local += __shfl_xor(local, m, 64);
  if ((tid & 63) == 0) red[tid >> 6] = local;
  __syncthreads();
  if (tid == 0) {
    float t = red[0] + red[1] + red[2] + red[3];
    out[0] = -t / (float)NB;
  }
}

extern "C" void kernel_launch(void* const* d_in, const int* in_sizes, int n_in,
                              void* d_out, int out_size, void* d_ws, size_t ws_size,
                              hipStream_t stream) {
  const float* centers = (const float*)d_in[0];   // [1000][512] f32
  const float* feats   = (const float*)d_in[1];   // [4096][512] f32
  const int*   targets = (const int*)d_in[2];     // [4096] i32
  const float* ood     = (const float*)d_in[3];   // [4096][512] f32
  const int*   pseudo  = (const int*)d_in[4];     // [4096] i32

  char* ws = (char*)d_ws;
  unsigned char* fall  = (unsigned char*)(ws + OFF_FALL);
  unsigned*      cntP  = (unsigned*)(ws + OFF_CNTP);
  unsigned*      cntTP = (unsigned*)(ws + OFF_CNTTP);
  float*         Sacc  = (float*)(ws + OFF_S);
  float*         Pacc  = (float*)(ws + OFF_P);

  prep_k<<<dim3((NPAD * 32) / 256), 256, 0, stream>>>(centers, feats, ood, targets, pseudo,
                                                      fall, cntP, cntTP, Sacc);
  gemm_fused<<<dim3(NPAD / BN, NB / BM), 256, 0, stream>>>(fall, targets, pseudo, cntP, Sacc, Pacc);
  finalize_k<<<1, 256, 0, stream>>>(Sacc, Pacc, targets, cntTP, (float*)d_out);
}

// Round 14
// 130.260 us; speedup vs baseline: 1.5607x; 1.0781x over previous
//
#include <hip/hip_runtime.h>
#include <stdint.h>

// Problem constants
#define NUM_C 1000
#define NB    4096
#define NCOL  9192          // NB + NUM_C + NO
#define NPAD  9216          // 576 row-tiles of 16
#define DK    512
#define BM    128
#define BN    256
#define INV_T 10.0f

typedef __attribute__((ext_vector_type(4))) float f32x4;

// workspace layout (bytes)
// fall: fragment-linear fp8 [r16=576][k32=16][lane=64][8B] = 4,718,592 B
#define OFF_FALL  0u
#define OFF_CNTP  4718592u           // uint[16][1024] partial hist (targets+pseudo)
#define OFF_CNTTP 4784128u           // uint[16][1024] partial hist (targets only)
#define OFF_S     4849664u           // float[4096]
#define OFF_P     4866048u           // float[4096]  (contiguous after S)

// f32 -> e4m3fn (OCP), software RNE fallback
__device__ __forceinline__ unsigned sw_e4m3(float x) {
  float ax = fabsf(x);
  unsigned s = (__float_as_uint(x) >> 24) & 0x80u;
  if (ax < 0.015625f) {
    int n = (int)rintf(ax * 512.0f);
    if (n >= 8) return s | 0x08u;
    return s | (unsigned)n;
  }
  if (ax >= 448.0f) return s | 0x7Eu;
  unsigned u = __float_as_uint(ax);
  int ee = (int)(u >> 23) - 127;
  float scale = __uint_as_float((unsigned)(3 - ee + 127) << 23);
  int qv = (int)rintf(ax * scale);
  if (qv == 16) { ee++; qv = 8; }
  return s | (unsigned)(((ee + 7) << 3) | (qv - 8));
}

template <bool HI>
__device__ __forceinline__ int cvt2(float a, float b, int old) {
#if __has_builtin(__builtin_amdgcn_cvt_pk_fp8_f32)
  return __builtin_amdgcn_cvt_pk_fp8_f32(a, b, old, HI);
#else
  unsigned pk = sw_e4m3(a) | (sw_e4m3(b) << 8);
  return HI ? (int)(((unsigned)old & 0x0000FFFFu) | (pk << 16))
            : (int)(((unsigned)old & 0xFFFF0000u) | pk);
#endif
}

// Build fall in FRAGMENT-LINEAR layout: one thread = one 8-byte MFMA fragment.
// idx = (r16*16 + k32)*64 + lane; holds row r16*16+(lane&15), k = k32*32+(lane>>4)*8.
// Write address = fall + idx*8 (perfectly lane-linear).
// blocks 0..15: partial histograms; 16..47: zero S/P
__global__ __launch_bounds__(256) void prep_k(const float* __restrict__ centers,
                                              const float* __restrict__ feats,
                                              const float* __restrict__ ood,
                                              const int* __restrict__ targets,
                                              const int* __restrict__ pseudo,
                                              unsigned long long* __restrict__ fall,
                                              unsigned* __restrict__ cntP,
                                              unsigned* __restrict__ cntTP,
                                              float* __restrict__ SP) {
  __shared__ unsigned hc[1024];
  __shared__ unsigned hct[1024];
  const int tid = threadIdx.x;

  int idx  = blockIdx.x * 256 + tid;      // 0 .. 589823
  int lane = idx & 63;
  int k32  = (idx >> 6) & 15;
  int r16  = idx >> 10;
  int row  = r16 * 16 + (lane & 15);
  int k    = k32 * 32 + (lane >> 4) * 8;

  const float* src = nullptr;
  if (row < NB)              src = feats   + (size_t)row * DK + k;
  else if (row < NB + NUM_C) src = centers + (size_t)(row - NB) * DK + k;
  else if (row < NCOL)       src = ood     + (size_t)(row - NB - NUM_C) * DK + k;
  unsigned long long frag = 0ull;
  if (src) {
    float4 v0 = *(const float4*)(src);
    float4 v1 = *(const float4*)(src + 4);
    int p0 = 0, p1 = 0;
    p0 = cvt2<false>(v0.x, v0.y, p0);
    p0 = cvt2<true>(v0.z, v0.w, p0);
    p1 = cvt2<false>(v1.x, v1.y, p1);
    p1 = cvt2<true>(v1.z, v1.w, p1);
    frag = (unsigned long long)(unsigned)p0 | ((unsigned long long)(unsigned)p1 << 32);
  }
  fall[idx] = frag;

  if (blockIdx.x < 16) {
    for (int kk = tid; kk < 1024; kk += 256) { hc[kk] = 0u; hct[kk] = 0u; }
    __syncthreads();
    int i = blockIdx.x * 256 + tid;      // 0..4095
    int t = targets[i];
    atomicAdd(&hc[t], 1u);
    atomicAdd(&hct[t], 1u);
    atomicAdd(&hc[pseudo[i]], 1u);
    __syncthreads();
    for (int kk = tid; kk < 1024; kk += 256) {
      cntP[blockIdx.x * 1024 + kk]  = hc[kk];
      cntTP[blockIdx.x * 1024 + kk] = hct[kk];
    }
  } else if (blockIdx.x < 48) {
    SP[(blockIdx.x - 16) * 256 + tid] = 0.0f;   // zeros S[4096] then P[4096]
  }
}

// Fused fp8 GEMM 128x256: NO LDS staging, NO K-loop barriers.
// Fragments loaded directly from fragment-linear fall: each wave-load is one
// coalesced 512B global_load_dwordx2. Register double-buffer; compiler waitcnts.
__global__ __launch_bounds__(256, 2) void gemm_fused(const unsigned char* __restrict__ fall,
                                                     const int* __restrict__ targets,
                                                     const int* __restrict__ pseudo,
                                                     const unsigned* __restrict__ cntP,
                                                     float* __restrict__ Sacc,
                                                     float* __restrict__ Pacc) {
  __shared__ int    sLbl[BN];
  __shared__ float  sRw0[BN];
  __shared__ float  sRw1[BN];
  __shared__ int    sTgt[BM];

  const int tid   = threadIdx.x;
  const int nTile = blockIdx.x;   // 36
  const int mTile = blockIdx.y;   // 32
  const int lane  = tid & 63;
  const int wv    = tid >> 6;     // wave 0..3
  const int wm    = wv >> 1;      // row half (64 rows = 4 row-tiles)
  const int wn    = wv & 1;       // col half (128 cols = 8 row-tiles of B)
  const int q     = lane >> 4;    // k-quad
  const int cIdx  = lane & 15;

  // per-column tables (lbl, 1/w, 1/(w-1)); per-row targets. w = 1 + sum of partials.
  {
    int j = nTile * BN + tid;
    int lbl, tac;
    if (j >= NCOL)         { lbl = -1; tac = -1; }
    else if (j < NB)       { tac = targets[j]; lbl = tac; }
    else if (j < NB+NUM_C) { tac = j - NB;     lbl = tac; }
    else                   { tac = pseudo[j - NB - NUM_C]; lbl = NUM_C; }
    sLbl[tid] = lbl;
    if (tac >= 0) {
      unsigned c = 1u;
#pragma unroll
      for (int b = 0; b < 16; b++) c += cntP[b * 1024 + tac];
      float w = (float)c;
      sRw0[tid] = 1.0f / w;
      sRw1[tid] = 1.0f / (w - 1.0f);  // only selected when a positive exists => w>=2
    } else {
      sRw0[tid] = 0.f;
      sRw1[tid] = 0.f;
    }
    if (tid < BM) sTgt[tid] = targets[mTile * BM + tid];
  }
  __syncthreads();   // tables ready; only barrier in the kernel

  f32x4 acc[4][8];
#pragma unroll
  for (int mi = 0; mi < 4; mi++)
#pragma unroll
    for (int ni = 0; ni < 8; ni++)
      acc[mi][ni] = (f32x4){0.f, 0.f, 0.f, 0.f};

  // fragment-linear bases: tile t at k-slab k32 -> fall + (t*16 + k32)*512 + lane*8
  // A row-tiles: mTile*8 + wm*4 + mi ; B row-tiles: nTile*16 + wn*8 + ni
  const unsigned char* aPtr = fall + ((size_t)(mTile * 8 + wm * 4))  * 8192 + lane * 8;
  const unsigned char* bPtr = fall + ((size_t)(nTile * 16 + wn * 8)) * 8192 + lane * 8;

  long long aCur[4], bCur[8], aNxt[4], bNxt[8];
#pragma unroll
  for (int mi = 0; mi < 4; mi++) aCur[mi] = *(const long long*)(aPtr + mi * 8192);
#pragma unroll
  for (int ni = 0; ni < 8; ni++) bCur[ni] = *(const long long*)(bPtr + ni * 8192);

#pragma unroll
  for (int it = 0; it < 16; it++) {
    if (it < 15) {
      const int ko = (it + 1) * 512;
#pragma unroll
      for (int mi = 0; mi < 4; mi++) aNxt[mi] = *(const long long*)(aPtr + mi * 8192 + ko);
#pragma unroll
      for (int ni = 0; ni < 8; ni++) bNxt[ni] = *(const long long*)(bPtr + ni * 8192 + ko);
    }
#pragma unroll
    for (int mi = 0; mi < 4; mi++)
#pragma unroll
      for (int ni = 0; ni < 8; ni++)
        acc[mi][ni] = __builtin_amdgcn_mfma_f32_16x16x32_fp8_fp8(aCur[mi], bCur[ni], acc[mi][ni], 0, 0, 0);
    if (it < 15) {
#pragma unroll
      for (int mi = 0; mi < 4; mi++) aCur[mi] = aNxt[mi];
#pragma unroll
      for (int ni = 0; ni < 8; ni++) bCur[ni] = bNxt[ni];
    }
  }

  // Epilogue: l = acc*10; S += exp(l-10) * (diag?0 : pos?1/(w-1) : 1/w); P += pos?l:0
  float vS[16], vP[16];
#pragma unroll
  for (int s = 0; s < 16; s++) { vS[s] = 0.f; vP[s] = 0.f; }

#pragma unroll
  for (int ni = 0; ni < 8; ni++) {
    int jloc = wn * 128 + ni * 16 + cIdx;
    int j    = nTile * BN + jloc;
    int lblj = sLbl[jloc];
    float rw0 = sRw0[jloc], rw1 = sRw1[jloc];
#pragma unroll
    for (int mi = 0; mi < 4; mi++) {
      f32x4 a = acc[mi][ni];
#pragma unroll
      for (int r = 0; r < 4; r++) {
        int iloc = wm * 64 + mi * 16 + q * 4 + r;
        int i    = mTile * BM + iloc;
        int ti   = sTgt[iloc];
        float l  = a[r] * INV_T;
        bool diag = (j == i);
        bool pos  = (lblj == ti) && !diag;
        float rw  = diag ? 0.0f : (pos ? rw1 : rw0);
        float e   = __expf(l - 10.0f) * rw;
        vS[mi * 4 + r] += e;
        vP[mi * 4 + r] += pos ? l : 0.0f;
      }
    }
  }

  // fully-static value-halving butterfly over the 16 cIdx lanes (15 shuffle pairs)
#define RED_STEP(m, s, h)                                        \
  {                                                              \
    float sendS = (cIdx & (m)) ? vS[(s)] : vS[(s) + (h)];        \
    float sendP = (cIdx & (m)) ? vP[(s)] : vP[(s) + (h)];        \
    float rS = __shfl_xor(sendS, (m), 64);                       \
    float rP = __shfl_xor(sendP, (m), 64);                       \
    vS[(s)] = ((cIdx & (m)) ? vS[(s) + (h)] : vS[(s)]) + rS;     \
    vP[(s)] = ((cIdx & (m)) ? vP[(s) + (h)] : vP[(s)]) + rP;     \
  }
  RED_STEP(8, 0, 8) RED_STEP(8, 1, 8) RED_STEP(8, 2, 8) RED_STEP(8, 3, 8)
  RED_STEP(8, 4, 8) RED_STEP(8, 5, 8) RED_STEP(8, 6, 8) RED_STEP(8, 7, 8)
  RED_STEP(4, 0, 4) RED_STEP(4, 1, 4) RED_STEP(4, 2, 4) RED_STEP(4, 3, 4)
  RED_STEP(2, 0, 2) RED_STEP(2, 1, 2)
  RED_STEP(1, 0, 1)
#undef RED_STEP

  {
    int rowLoc = wm * 64 + (cIdx >> 2) * 16 + q * 4 + (cIdx & 3);
    int i = mTile * BM + rowLoc;
    atomicAdd(&Sacc[i], vS[0]);
    atomicAdd(&Pacc[i], vP[0]);
  }
}

// loss = -mean( P/npos - 10 - log S );  npos_i = sum_b cntTP[b][targets[i]]
__global__ __launch_bounds__(256) void finalize_k(const float* __restrict__ S,
                                                  const float* __restrict__ P,
                                                  const int* __restrict__ targets,
                                                  const unsigned* __restrict__ cntTP,
                                                  float* __restrict__ out) {
  __shared__ unsigned ct[1024];
  __shared__ float red[4];
  int tid = threadIdx.x;
  for (int k = tid; k < 1024; k += 256) {
    unsigned c = 0u;
#pragma unroll
    for (int b = 0; b < 16; b++) c += cntTP[b * 1024 + k];
    ct[k] = c;
  }
  __syncthreads();
  float local = 0.f;
  for (int i = tid; i < NB; i += 256) {
    float npos = (float)ct[targets[i]];
    local += P[i] / npos - INV_T - __logf(S[i]);
  }
  for (int m = 1; m < 64; m <<= 1) local += __shfl_xor(local, m, 64);
  if ((tid & 63) == 0) red[tid >> 6] = local;
  __syncthreads();
  if (tid == 0) {
    float t = red[0] + red[1] + red[2] + red[3];
    out[0] = -t / (float)NB;
  }
}

extern "C" void kernel_launch(void* const* d_in, const int* in_sizes, int n_in,
                              void* d_out, int out_size, void* d_ws, size_t ws_size,
                              hipStream_t stream) {
  const float* centers = (const float*)d_in[0];   // [1000][512] f32
  const float* feats   = (const float*)d_in[1];   // [4096][512] f32
  const int*   targets = (const int*)d_in[2];     // [4096] i32
  const float* ood     = (const float*)d_in[3];   // [4096][512] f32
  const int*   pseudo  = (const int*)d_in[4];     // [4096] i32

  char* ws = (char*)d_ws;
  unsigned long long* fall  = (unsigned long long*)(ws + OFF_FALL);
  unsigned*           cntP  = (unsigned*)(ws + OFF_CNTP);
  unsigned*           cntTP = (unsigned*)(ws + OFF_CNTTP);
  float*              Sacc  = (float*)(ws + OFF_S);
  float*              Pacc  = (float*)(ws + OFF_P);

  prep_k<<<dim3((NPAD * 64) / 256), 256, 0, stream>>>(centers, feats, ood, targets, pseudo,
                                                      fall, cntP, cntTP, Sacc);
  gemm_fused<<<dim3(NPAD / BN, NB / BM), 256, 0, stream>>>((const unsigned char*)fall, targets,
                                                           pseudo, cntP, Sacc, Pacc);
  finalize_k<<<1, 256, 0, stream>>>(Sacc, Pacc, targets, cntTP, (float*)d_out);
}

// Round 15
// 122.507 us; speedup vs baseline: 1.6594x; 1.0633x over previous
//
#include <hip/hip_runtime.h>
#include <stdint.h>

// Problem constants
#define NUM_C 1000
#define NB    4096
#define NCOL  9192          // NB + NUM_C + NO
#define NPAD  9216          // 576 row-tiles of 16
#define DK    512
#define BM    128
#define BN    256
#define INV_T 10.0f

typedef __attribute__((ext_vector_type(4))) float f32x4;

// workspace layout (bytes)
// fall: paired fragment-linear fp8 [tile=576][kp=8][lane=64][16B] = 4,718,592 B
//   thread (t,kp,lane) 16B = frag(k32=2kp) 8B | frag(k32=2kp+1) 8B
//   frag(k32): row = t*16+(lane&15), k = k32*32+(lane>>4)*8 .. +7
#define OFF_FALL  0u
#define OFF_CNTP  4718592u           // uint[16][1024] partial hist (targets+pseudo)
#define OFF_CNTTP 4784128u           // uint[16][1024] partial hist (targets only)
#define OFF_S     4849664u           // float[4096]
#define OFF_P     4866048u           // float[4096]  (contiguous after S)

__device__ __forceinline__ void async16(const void* g, void* l) {
  __builtin_amdgcn_global_load_lds((const __attribute__((address_space(1))) void*)g,
                                   (__attribute__((address_space(3))) void*)l,
                                   16, 0, 0);
}

// f32 -> e4m3fn (OCP), software RNE fallback
__device__ __forceinline__ unsigned sw_e4m3(float x) {
  float ax = fabsf(x);
  unsigned s = (__float_as_uint(x) >> 24) & 0x80u;
  if (ax < 0.015625f) {
    int n = (int)rintf(ax * 512.0f);
    if (n >= 8) return s | 0x08u;
    return s | (unsigned)n;
  }
  if (ax >= 448.0f) return s | 0x7Eu;
  unsigned u = __float_as_uint(ax);
  int ee = (int)(u >> 23) - 127;
  float scale = __uint_as_float((unsigned)(3 - ee + 127) << 23);
  int qv = (int)rintf(ax * scale);
  if (qv == 16) { ee++; qv = 8; }
  return s | (unsigned)(((ee + 7) << 3) | (qv - 8));
}

template <bool HI>
__device__ __forceinline__ int cvt2(float a, float b, int old) {
#if __has_builtin(__builtin_amdgcn_cvt_pk_fp8_f32)
  return __builtin_amdgcn_cvt_pk_fp8_f32(a, b, old, HI);
#else
  unsigned pk = sw_e4m3(a) | (sw_e4m3(b) << 8);
  return HI ? (int)(((unsigned)old & 0x0000FFFFu) | (pk << 16))
            : (int)(((unsigned)old & 0xFFFF0000u) | pk);
#endif
}

__device__ __forceinline__ long long mk_ll(unsigned lo, unsigned hi) {
  return (long long)(((unsigned long long)hi << 32) | lo);
}

// Build fall in paired fragment-linear layout: one thread = one 16B pair.
// blocks 0..15: partial histograms; 16..47: zero S/P
__global__ __launch_bounds__(256) void prep_k(const float* __restrict__ centers,
                                              const float* __restrict__ feats,
                                              const float* __restrict__ ood,
                                              const int* __restrict__ targets,
                                              const int* __restrict__ pseudo,
                                              uint4* __restrict__ fall,
                                              unsigned* __restrict__ cntP,
                                              unsigned* __restrict__ cntTP,
                                              float* __restrict__ SP) {
  __shared__ unsigned hc[1024];
  __shared__ unsigned hct[1024];
  const int tid = threadIdx.x;

  int idx  = blockIdx.x * 256 + tid;      // 0 .. 294911
  int lane = idx & 63;
  int kp   = (idx >> 6) & 7;
  int t    = idx >> 9;
  int row  = t * 16 + (lane & 15);
  int k0   = kp * 64 + (lane >> 4) * 8;   // frag s=0; s=1 at k0+32

  const float* src = nullptr;
  if (row < NB)              src = feats   + (size_t)row * DK;
  else if (row < NB + NUM_C) src = centers + (size_t)(row - NB) * DK;
  else if (row < NCOL)       src = ood     + (size_t)(row - NB - NUM_C) * DK;
  uint4 out = make_uint4(0u, 0u, 0u, 0u);
  if (src) {
    float4 v0 = *(const float4*)(src + k0);
    float4 v1 = *(const float4*)(src + k0 + 4);
    float4 v2 = *(const float4*)(src + k0 + 32);
    float4 v3 = *(const float4*)(src + k0 + 36);
    int p;
    p = 0; p = cvt2<false>(v0.x, v0.y, p); p = cvt2<true>(v0.z, v0.w, p); out.x = (unsigned)p;
    p = 0; p = cvt2<false>(v1.x, v1.y, p); p = cvt2<true>(v1.z, v1.w, p); out.y = (unsigned)p;
    p = 0; p = cvt2<false>(v2.x, v2.y, p); p = cvt2<true>(v2.z, v2.w, p); out.z = (unsigned)p;
    p = 0; p = cvt2<false>(v3.x, v3.y, p); p = cvt2<true>(v3.z, v3.w, p); out.w = (unsigned)p;
  }
  fall[idx] = out;

  if (blockIdx.x < 16) {
    for (int kk = tid; kk < 1024; kk += 256) { hc[kk] = 0u; hct[kk] = 0u; }
    __syncthreads();
    int i = blockIdx.x * 256 + tid;      // 0..4095
    int tt = targets[i];
    atomicAdd(&hc[tt], 1u);
    atomicAdd(&hct[tt], 1u);
    atomicAdd(&hc[pseudo[i]], 1u);
    __syncthreads();
    for (int kk = tid; kk < 1024; kk += 256) {
      cntP[blockIdx.x * 1024 + kk]  = hc[kk];
      cntTP[blockIdx.x * 1024 + kk] = hct[kk];
    }
  } else if (blockIdx.x < 48) {
    SP[(blockIdx.x - 16) * 256 + tid] = 0.0f;   // zeros S[4096] then P[4096]
  }
}

// Fused fp8 GEMM 128x256: A tile (64 KB) resident in LDS (one prologue copy),
// B direct from global as paired dwordx4 (2 k-slabs per load, ping-pong).
// Zero barriers in the K-loop.
__global__ __launch_bounds__(256, 2) void gemm_fused(const unsigned char* __restrict__ fall,
                                                     const int* __restrict__ targets,
                                                     const int* __restrict__ pseudo,
                                                     const unsigned* __restrict__ cntP,
                                                     float* __restrict__ Sacc,
                                                     float* __restrict__ Pacc) {
  __shared__ unsigned char Alds[65536];   // block's A: tiles mTile*8..+7, fall-layout copy
  __shared__ int    sLbl[BN];
  __shared__ float  sRw0[BN];
  __shared__ float  sRw1[BN];
  __shared__ int    sTgt[BM];

  const int tid   = threadIdx.x;
  const int nTile = blockIdx.x;   // 36
  const int mTile = blockIdx.y;   // 32
  const int lane  = tid & 63;
  const int wv    = tid >> 6;     // wave 0..3
  const int wm    = wv >> 1;      // row half (tiles wm*4..+3)
  const int wn    = wv & 1;       // col half (tiles wn*8..+7)
  const int q     = lane >> 4;    // k-quad
  const int cIdx  = lane & 15;

  // prologue: copy A (contiguous 64 KB of fall) into LDS via DMA
  {
    const unsigned char* aSrc = fall + (size_t)(mTile * 8) * 8192;
#pragma unroll
    for (int i = 0; i < 16; i++)
      async16(aSrc + (i * 256 + tid) * 16, &Alds[(i * 256 + tid) * 16]);
  }

  // per-column tables (lbl, 1/w, 1/(w-1)); per-row targets. w = 1 + sum of partials.
  {
    int j = nTile * BN + tid;
    int lbl, tac;
    if (j >= NCOL)         { lbl = -1; tac = -1; }
    else if (j < NB)       { tac = targets[j]; lbl = tac; }
    else if (j < NB+NUM_C) { tac = j - NB;     lbl = tac; }
    else                   { tac = pseudo[j - NB - NUM_C]; lbl = NUM_C; }
    sLbl[tid] = lbl;
    if (tac >= 0) {
      unsigned c = 1u;
#pragma unroll
      for (int b = 0; b < 16; b++) c += cntP[b * 1024 + tac];
      float w = (float)c;
      sRw0[tid] = 1.0f / w;
      sRw1[tid] = 1.0f / (w - 1.0f);  // only selected when a positive exists => w>=2
    } else {
      sRw0[tid] = 0.f;
      sRw1[tid] = 0.f;
    }
    if (tid < BM) sTgt[tid] = targets[mTile * BM + tid];
  }

  f32x4 acc[4][8];
#pragma unroll
  for (int mi = 0; mi < 4; mi++)
#pragma unroll
    for (int ni = 0; ni < 8; ni++)
      acc[mi][ni] = (f32x4){0.f, 0.f, 0.f, 0.f};

  // B base: tile (nTile*16 + wn*8 + ni) at fall + tile*8192 + kp*1024 + lane*16
  const unsigned char* bBase = fall + (size_t)(nTile * 16 + wn * 8) * 8192 + lane * 16;
  // A LDS base for this wave: tile (wm*4+mi), same internal layout
  const unsigned aBase = (unsigned)(wm * 4) * 8192u + (unsigned)lane * 16u;

  uint4 bCur[8], bNxt[8];
#pragma unroll
  for (int ni = 0; ni < 8; ni++)
    bCur[ni] = *(const uint4*)(bBase + ni * 8192);

  __syncthreads();   // A landed (vmcnt drain) + tables ready; only barrier

#pragma unroll
  for (int kp = 0; kp < 8; kp++) {
    if (kp < 7) {
#pragma unroll
      for (int ni = 0; ni < 8; ni++)
        bNxt[ni] = *(const uint4*)(bBase + ni * 8192 + (kp + 1) * 1024);
    }
    long long af0[4], af1[4];
#pragma unroll
    for (int mi = 0; mi < 4; mi++) {
      af0[mi] = *(const long long*)&Alds[aBase + mi * 8192 + kp * 1024];
      af1[mi] = *(const long long*)&Alds[aBase + mi * 8192 + kp * 1024 + 8];
    }
#pragma unroll
    for (int mi = 0; mi < 4; mi++)
#pragma unroll
      for (int ni = 0; ni < 8; ni++)
        acc[mi][ni] = __builtin_amdgcn_mfma_f32_16x16x32_fp8_fp8(af0[mi], mk_ll(bCur[ni].x, bCur[ni].y), acc[mi][ni], 0, 0, 0);
#pragma unroll
    for (int mi = 0; mi < 4; mi++)
#pragma unroll
      for (int ni = 0; ni < 8; ni++)
        acc[mi][ni] = __builtin_amdgcn_mfma_f32_16x16x32_fp8_fp8(af1[mi], mk_ll(bCur[ni].z, bCur[ni].w), acc[mi][ni], 0, 0, 0);
    if (kp < 7) {
#pragma unroll
      for (int ni = 0; ni < 8; ni++) bCur[ni] = bNxt[ni];
    }
  }

  // Epilogue: l = acc*10; S += exp(l-10) * (diag?0 : pos?1/(w-1) : 1/w); P += pos?l:0
  float vS[16], vP[16];
#pragma unroll
  for (int s = 0; s < 16; s++) { vS[s] = 0.f; vP[s] = 0.f; }

#pragma unroll
  for (int ni = 0; ni < 8; ni++) {
    int jloc = wn * 128 + ni * 16 + cIdx;
    int j    = nTile * BN + jloc;
    int lblj = sLbl[jloc];
    float rw0 = sRw0[jloc], rw1 = sRw1[jloc];
#pragma unroll
    for (int mi = 0; mi < 4; mi++) {
      f32x4 a = acc[mi][ni];
#pragma unroll
      for (int r = 0; r < 4; r++) {
        int iloc = wm * 64 + mi * 16 + q * 4 + r;
        int i    = mTile * BM + iloc;
        int ti   = sTgt[iloc];
        float l  = a[r] * INV_T;
        bool diag = (j == i);
        bool pos  = (lblj == ti) && !diag;
        float rw  = diag ? 0.0f : (pos ? rw1 : rw0);
        float e   = __expf(l - 10.0f) * rw;
        vS[mi * 4 + r] += e;
        vP[mi * 4 + r] += pos ? l : 0.0f;
      }
    }
  }

  // fully-static value-halving butterfly over the 16 cIdx lanes (15 shuffle pairs)
#define RED_STEP(m, s, h)                                        \
  {                                                              \
    float sendS = (cIdx & (m)) ? vS[(s)] : vS[(s) + (h)];        \
    float sendP = (cIdx & (m)) ? vP[(s)] : vP[(s) + (h)];        \
    float rS = __shfl_xor(sendS, (m), 64);                       \
    float rP = __shfl_xor(sendP, (m), 64);                       \
    vS[(s)] = ((cIdx & (m)) ? vS[(s) + (h)] : vS[(s)]) + rS;     \
    vP[(s)] = ((cIdx & (m)) ? vP[(s) + (h)] : vP[(s)]) + rP;     \
  }
  RED_STEP(8, 0, 8) RED_STEP(8, 1, 8) RED_STEP(8, 2, 8) RED_STEP(8, 3, 8)
  RED_STEP(8, 4, 8) RED_STEP(8, 5, 8) RED_STEP(8, 6, 8) RED_STEP(8, 7, 8)
  RED_STEP(4, 0, 4) RED_STEP(4, 1, 4) RED_STEP(4, 2, 4) RED_STEP(4, 3, 4)
  RED_STEP(2, 0, 2) RED_STEP(2, 1, 2)
  RED_STEP(1, 0, 1)
#undef RED_STEP

  {
    int rowLoc = wm * 64 + (cIdx >> 2) * 16 + q * 4 + (cIdx & 3);
    int i = mTile * BM + rowLoc;
    atomicAdd(&Sacc[i], vS[0]);
    atomicAdd(&Pacc[i], vP[0]);
  }
}

// loss = -mean( P/npos - 10 - log S );  npos_i = sum_b cntTP[b][targets[i]]
__global__ __launch_bounds__(256) void finalize_k(const float* __restrict__ S,
                                                  const float* __restrict__ P,
                                                  const int* __restrict__ targets,
                                                  const unsigned* __restrict__ cntTP,
                                                  float* __restrict__ out) {
  __shared__ unsigned ct[1024];
  __shared__ float red[4];
  int tid = threadIdx.x;
  for (int k = tid; k < 1024; k += 256) {
    unsigned c = 0u;
#pragma unroll
    for (int b = 0; b < 16; b++) c += cntTP[b * 1024 + k];
    ct[k] = c;
  }
  __syncthreads();
  float local = 0.f;
  for (int i = tid; i < NB; i += 256) {
    float npos = (float)ct[targets[i]];
    local += P[i] / npos - INV_T - __logf(S[i]);
  }
  for (int m = 1; m < 64; m <<= 1) local += __shfl_xor(local, m, 64);
  if ((tid & 63) == 0) red[tid >> 6] = local;
  __syncthreads();
  if (tid == 0) {
    float t = red[0] + red[1] + red[2] + red[3];
    out[0] = -t / (float)NB;
  }
}

extern "C" void kernel_launch(void* const* d_in, const int* in_sizes, int n_in,
                              void* d_out, int out_size, void* d_ws, size_t ws_size,
                              hipStream_t stream) {
  const float* centers = (const float*)d_in[0];   // [1000][512] f32
  const float* feats   = (const float*)d_in[1];   // [4096][512] f32
  const int*   targets = (const int*)d_in[2];     // [4096] i32
  const float* ood     = (const float*)d_in[3];   // [4096][512] f32
  const int*   pseudo  = (const int*)d_in[4];     // [4096] i32

  char* ws = (char*)d_ws;
  uint4*    fall  = (uint4*)(ws + OFF_FALL);
  unsigned* cntP  = (unsigned*)(ws + OFF_CNTP);
  unsigned* cntTP = (unsigned*)(ws + OFF_CNTTP);
  float*    Sacc  = (float*)(ws + OFF_S);
  float*    Pacc  = (float*)(ws + OFF_P);

  prep_k<<<dim3((NPAD * 32) / 256), 256, 0, stream>>>(centers, feats, ood, targets, pseudo,
                                                      fall, cntP, cntTP, Sacc);
  gemm_fused<<<dim3(NPAD / BN, NB / BM), 256, 0, stream>>>((const unsigned char*)fall, targets,
                                                           pseudo, cntP, Sacc, Pacc);
  finalize_k<<<1, 256, 0, stream>>>(Sacc, Pacc, targets, cntTP, (float*)d_out);
}

// Round 16
// 118.787 us; speedup vs baseline: 1.7114x; 1.0313x over previous
//
#include <hip/hip_runtime.h>
#include <stdint.h>

// Problem constants
#define NUM_C 1000
#define NB    4096
#define NCOL  9192          // NB + NUM_C + NO
#define NPAD  9216          // 576 row-tiles of 16
#define DK    512
#define BM    128
#define BN    256
#define INV_T 10.0f

typedef __attribute__((ext_vector_type(4))) float f32x4;

// workspace layout (bytes)
// fall: paired fragment-linear fp8 [tile=576][kp=8][lane=64][16B] = 4,718,592 B
#define OFF_FALL  0u
#define OFF_CNT   4718592u           // uint[1024] final hist (targets+pseudo)
#define OFF_CNTT  4722688u           // uint[1024] final hist (targets only)
#define OFF_S     4726784u           // float[4096]
#define OFF_P     4743168u           // float[4096]  (contiguous after S)

__device__ __forceinline__ void async16(const void* g, void* l) {
  __builtin_amdgcn_global_load_lds((const __attribute__((address_space(1))) void*)g,
                                   (__attribute__((address_space(3))) void*)l,
                                   16, 0, 0);
}

// f32 -> e4m3fn (OCP), software RNE fallback
__device__ __forceinline__ unsigned sw_e4m3(float x) {
  float ax = fabsf(x);
  unsigned s = (__float_as_uint(x) >> 24) & 0x80u;
  if (ax < 0.015625f) {
    int n = (int)rintf(ax * 512.0f);
    if (n >= 8) return s | 0x08u;
    return s | (unsigned)n;
  }
  if (ax >= 448.0f) return s | 0x7Eu;
  unsigned u = __float_as_uint(ax);
  int ee = (int)(u >> 23) - 127;
  float scale = __uint_as_float((unsigned)(3 - ee + 127) << 23);
  int qv = (int)rintf(ax * scale);
  if (qv == 16) { ee++; qv = 8; }
  return s | (unsigned)(((ee + 7) << 3) | (qv - 8));
}

template <bool HI>
__device__ __forceinline__ int cvt2(float a, float b, int old) {
#if __has_builtin(__builtin_amdgcn_cvt_pk_fp8_f32)
  return __builtin_amdgcn_cvt_pk_fp8_f32(a, b, old, HI);
#else
  unsigned pk = sw_e4m3(a) | (sw_e4m3(b) << 8);
  return HI ? (int)(((unsigned)old & 0x0000FFFFu) | (pk << 16))
            : (int)(((unsigned)old & 0xFFFF0000u) | pk);
#endif
}

__device__ __forceinline__ long long mk_ll(unsigned lo, unsigned hi) {
  return (long long)(((unsigned long long)hi << 32) | lo);
}

// Build fall in paired fragment-linear layout: one thread = one 16B pair.
// blocks 0..15: LDS partial histograms -> global atomicAdd into cnt/cntT (pre-zeroed)
// blocks 16..47: zero S/P
__global__ __launch_bounds__(256) void prep_k(const float* __restrict__ centers,
                                              const float* __restrict__ feats,
                                              const float* __restrict__ ood,
                                              const int* __restrict__ targets,
                                              const int* __restrict__ pseudo,
                                              uint4* __restrict__ fall,
                                              unsigned* __restrict__ cnt,
                                              unsigned* __restrict__ cntT,
                                              float* __restrict__ SP) {
  __shared__ unsigned hc[1024];
  __shared__ unsigned hct[1024];
  const int tid = threadIdx.x;

  int idx  = blockIdx.x * 256 + tid;      // 0 .. 294911
  int lane = idx & 63;
  int kp   = (idx >> 6) & 7;
  int t    = idx >> 9;
  int row  = t * 16 + (lane & 15);
  int k0   = kp * 64 + (lane >> 4) * 8;   // frag s=0; s=1 at k0+32

  const float* src = nullptr;
  if (row < NB)              src = feats   + (size_t)row * DK;
  else if (row < NB + NUM_C) src = centers + (size_t)(row - NB) * DK;
  else if (row < NCOL)       src = ood     + (size_t)(row - NB - NUM_C) * DK;
  uint4 out = make_uint4(0u, 0u, 0u, 0u);
  if (src) {
    float4 v0 = *(const float4*)(src + k0);
    float4 v1 = *(const float4*)(src + k0 + 4);
    float4 v2 = *(const float4*)(src + k0 + 32);
    float4 v3 = *(const float4*)(src + k0 + 36);
    int p;
    p = 0; p = cvt2<false>(v0.x, v0.y, p); p = cvt2<true>(v0.z, v0.w, p); out.x = (unsigned)p;
    p = 0; p = cvt2<false>(v1.x, v1.y, p); p = cvt2<true>(v1.z, v1.w, p); out.y = (unsigned)p;
    p = 0; p = cvt2<false>(v2.x, v2.y, p); p = cvt2<true>(v2.z, v2.w, p); out.z = (unsigned)p;
    p = 0; p = cvt2<false>(v3.x, v3.y, p); p = cvt2<true>(v3.z, v3.w, p); out.w = (unsigned)p;
  }
  fall[idx] = out;

  if (blockIdx.x < 16) {
    for (int kk = tid; kk < 1024; kk += 256) { hc[kk] = 0u; hct[kk] = 0u; }
    __syncthreads();
    int i = blockIdx.x * 256 + tid;      // 0..4095
    int tt = targets[i];
    atomicAdd(&hc[tt], 1u);
    atomicAdd(&hct[tt], 1u);
    atomicAdd(&hc[pseudo[i]], 1u);
    __syncthreads();
    for (int kk = tid; kk < 1024; kk += 256) {
      unsigned c = hc[kk], ct = hct[kk];
      if (c)  atomicAdd(&cnt[kk], c);    // device-scope by default
      if (ct) atomicAdd(&cntT[kk], ct);
    }
  } else if (blockIdx.x < 48) {
    SP[(blockIdx.x - 16) * 256 + tid] = 0.0f;   // zeros S[4096] then P[4096]
  }
}

// Fused fp8 GEMM 128x256: A tile (64 KB) resident in LDS (one prologue copy),
// B direct from global as paired dwordx4 (2 k-slabs per load, ping-pong).
// Zero barriers in the K-loop. Per-column weight = single cnt load.
__global__ __launch_bounds__(256, 2) void gemm_fused(const unsigned char* __restrict__ fall,
                                                     const int* __restrict__ targets,
                                                     const int* __restrict__ pseudo,
                                                     const unsigned* __restrict__ cnt,
                                                     float* __restrict__ Sacc,
                                                     float* __restrict__ Pacc) {
  __shared__ unsigned char Alds[65536];   // block's A: tiles mTile*8..+7, fall-layout copy
  __shared__ int    sLbl[BN];
  __shared__ float  sRw0[BN];
  __shared__ float  sRw1[BN];
  __shared__ int    sTgt[BM];

  const int tid   = threadIdx.x;
  const int nTile = blockIdx.x;   // 36
  const int mTile = blockIdx.y;   // 32
  const int lane  = tid & 63;
  const int wv    = tid >> 6;     // wave 0..3
  const int wm    = wv >> 1;      // row half (tiles wm*4..+3)
  const int wn    = wv & 1;       // col half (tiles wn*8..+7)
  const int q     = lane >> 4;    // k-quad
  const int cIdx  = lane & 15;

  // prologue: copy A (contiguous 64 KB of fall) into LDS via DMA
  {
    const unsigned char* aSrc = fall + (size_t)(mTile * 8) * 8192;
#pragma unroll
    for (int i = 0; i < 16; i++)
      async16(aSrc + (i * 256 + tid) * 16, &Alds[(i * 256 + tid) * 16]);
  }

  // per-column tables (lbl, 1/w, 1/(w-1)); per-row targets. w = 1 + cnt[tac].
  {
    int j = nTile * BN + tid;
    int lbl, tac;
    if (j >= NCOL)         { lbl = -1; tac = -1; }
    else if (j < NB)       { tac = targets[j]; lbl = tac; }
    else if (j < NB+NUM_C) { tac = j - NB;     lbl = tac; }
    else                   { tac = pseudo[j - NB - NUM_C]; lbl = NUM_C; }
    sLbl[tid] = lbl;
    if (tac >= 0) {
      float w = (float)(1u + cnt[tac]);
      sRw0[tid] = 1.0f / w;
      sRw1[tid] = 1.0f / (w - 1.0f);  // only selected when a positive exists => w>=2
    } else {
      sRw0[tid] = 0.f;
      sRw1[tid] = 0.f;
    }
    if (tid < BM) sTgt[tid] = targets[mTile * BM + tid];
  }

  f32x4 acc[4][8];
#pragma unroll
  for (int mi = 0; mi < 4; mi++)
#pragma unroll
    for (int ni = 0; ni < 8; ni++)
      acc[mi][ni] = (f32x4){0.f, 0.f, 0.f, 0.f};

  // B base: tile (nTile*16 + wn*8 + ni) at fall + tile*8192 + kp*1024 + lane*16
  const unsigned char* bBase = fall + (size_t)(nTile * 16 + wn * 8) * 8192 + lane * 16;
  // A LDS base for this wave: tile (wm*4+mi), same internal layout
  const unsigned aBase = (unsigned)(wm * 4) * 8192u + (unsigned)lane * 16u;

  uint4 bCur[8], bNxt[8];
#pragma unroll
  for (int ni = 0; ni < 8; ni++)
    bCur[ni] = *(const uint4*)(bBase + ni * 8192);

  __syncthreads();   // A landed (vmcnt drain) + tables ready; only barrier

#pragma unroll
  for (int kp = 0; kp < 8; kp++) {
    if (kp < 7) {
#pragma unroll
      for (int ni = 0; ni < 8; ni++)
        bNxt[ni] = *(const uint4*)(bBase + ni * 8192 + (kp + 1) * 1024);
    }
    long long af0[4], af1[4];
#pragma unroll
    for (int mi = 0; mi < 4; mi++) {
      af0[mi] = *(const long long*)&Alds[aBase + mi * 8192 + kp * 1024];
      af1[mi] = *(const long long*)&Alds[aBase + mi * 8192 + kp * 1024 + 8];
    }
#pragma unroll
    for (int mi = 0; mi < 4; mi++)
#pragma unroll
      for (int ni = 0; ni < 8; ni++)
        acc[mi][ni] = __builtin_amdgcn_mfma_f32_16x16x32_fp8_fp8(af0[mi], mk_ll(bCur[ni].x, bCur[ni].y), acc[mi][ni], 0, 0, 0);
#pragma unroll
    for (int mi = 0; mi < 4; mi++)
#pragma unroll
      for (int ni = 0; ni < 8; ni++)
        acc[mi][ni] = __builtin_amdgcn_mfma_f32_16x16x32_fp8_fp8(af1[mi], mk_ll(bCur[ni].z, bCur[ni].w), acc[mi][ni], 0, 0, 0);
    if (kp < 7) {
#pragma unroll
      for (int ni = 0; ni < 8; ni++) bCur[ni] = bNxt[ni];
    }
  }

  // Epilogue: l = acc*10; S += exp(l-10) * (diag?0 : pos?1/(w-1) : 1/w); P += pos?l:0
  float vS[16], vP[16];
#pragma unroll
  for (int s = 0; s < 16; s++) { vS[s] = 0.f; vP[s] = 0.f; }

#pragma unroll
  for (int ni = 0; ni < 8; ni++) {
    int jloc = wn * 128 + ni * 16 + cIdx;
    int j    = nTile * BN + jloc;
    int lblj = sLbl[jloc];
    float rw0 = sRw0[jloc], rw1 = sRw1[jloc];
#pragma unroll
    for (int mi = 0; mi < 4; mi++) {
      f32x4 a = acc[mi][ni];
#pragma unroll
      for (int r = 0; r < 4; r++) {
        int iloc = wm * 64 + mi * 16 + q * 4 + r;
        int i    = mTile * BM + iloc;
        int ti   = sTgt[iloc];
        float l  = a[r] * INV_T;
        bool diag = (j == i);
        bool pos  = (lblj == ti) && !diag;
        float rw  = diag ? 0.0f : (pos ? rw1 : rw0);
        float e   = __expf(l - 10.0f) * rw;
        vS[mi * 4 + r] += e;
        vP[mi * 4 + r] += pos ? l : 0.0f;
      }
    }
  }

  // fully-static value-halving butterfly over the 16 cIdx lanes (15 shuffle pairs)
#define RED_STEP(m, s, h)                                        \
  {                                                              \
    float sendS = (cIdx & (m)) ? vS[(s)] : vS[(s) + (h)];        \
    float sendP = (cIdx & (m)) ? vP[(s)] : vP[(s) + (h)];        \
    float rS = __shfl_xor(sendS, (m), 64);                       \
    float rP = __shfl_xor(sendP, (m), 64);                       \
    vS[(s)] = ((cIdx & (m)) ? vS[(s) + (h)] : vS[(s)]) + rS;     \
    vP[(s)] = ((cIdx & (m)) ? vP[(s) + (h)] : vP[(s)]) + rP;     \
  }
  RED_STEP(8, 0, 8) RED_STEP(8, 1, 8) RED_STEP(8, 2, 8) RED_STEP(8, 3, 8)
  RED_STEP(8, 4, 8) RED_STEP(8, 5, 8) RED_STEP(8, 6, 8) RED_STEP(8, 7, 8)
  RED_STEP(4, 0, 4) RED_STEP(4, 1, 4) RED_STEP(4, 2, 4) RED_STEP(4, 3, 4)
  RED_STEP(2, 0, 2) RED_STEP(2, 1, 2)
  RED_STEP(1, 0, 1)
#undef RED_STEP

  {
    int rowLoc = wm * 64 + (cIdx >> 2) * 16 + q * 4 + (cIdx & 3);
    int i = mTile * BM + rowLoc;
    atomicAdd(&Sacc[i], vS[0]);
    atomicAdd(&Pacc[i], vP[0]);
  }
}

// loss = -mean( P/npos - 10 - log S );  npos_i = cntT[targets[i]]
__global__ __launch_bounds__(256) void finalize_k(const float* __restrict__ S,
                                                  const float* __restrict__ P,
                                                  const int* __restrict__ targets,
                                                  const unsigned* __restrict__ cntT,
                                                  float* __restrict__ out) {
  __shared__ unsigned ct[1024];
  __shared__ float red[4];
  int tid = threadIdx.x;
  for (int k = tid; k < 1024; k += 256) ct[k] = cntT[k];
  __syncthreads();
  float local = 0.f;
  for (int i = tid; i < NB; i += 256) {
    float npos = (float)ct[targets[i]];
    local += P[i] / npos - INV_T - __logf(S[i]);
  }
  for (int m = 1; m < 64; m <<= 1) local += __shfl_xor(local, m, 64);
  if ((tid & 63) == 0) red[tid >> 6] = local;
  __syncthreads();
  if (tid == 0) {
    float t = red[0] + red[1] + red[2] + red[3];
    out[0] = -t / (float)NB;
  }
}

extern "C" void kernel_launch(void* const* d_in, const int* in_sizes, int n_in,
                              void* d_out, int out_size, void* d_ws, size_t ws_size,
                              hipStream_t stream) {
  const float* centers = (const float*)d_in[0];   // [1000][512] f32
  const float* feats   = (const float*)d_in[1];   // [4096][512] f32
  const int*   targets = (const int*)d_in[2];     // [4096] i32
  const float* ood     = (const float*)d_in[3];   // [4096][512] f32
  const int*   pseudo  = (const int*)d_in[4];     // [4096] i32

  char* ws = (char*)d_ws;
  uint4*    fall  = (uint4*)(ws + OFF_FALL);
  unsigned* cnt   = (unsigned*)(ws + OFF_CNT);
  unsigned* cntT  = (unsigned*)(ws + OFF_CNTT);
  float*    Sacc  = (float*)(ws + OFF_S);
  float*    Pacc  = (float*)(ws + OFF_P);

  hipMemsetAsync(ws + OFF_CNT, 0, 8192, stream);   // zero cnt + cntT
  prep_k<<<dim3((NPAD * 32) / 256), 256, 0, stream>>>(centers, feats, ood, targets, pseudo,
                                                      fall, cnt, cntT, Sacc);
  gemm_fused<<<dim3(NPAD / BN, NB / BM), 256, 0, stream>>>((const unsigned char*)fall, targets,
                                                           pseudo, cnt, Sacc, Pacc);
  finalize_k<<<1, 256, 0, stream>>>(Sacc, Pacc, targets, cntT, (float*)d_out);
}